// Round 8
// baseline (731.826 us; speedup 1.0000x reference)
//
#include <hip/hip_runtime.h>
#include <stdint.h>

// Problem constants (n=1, c=32, h=w=128, p=3)
#define NPT    16384        // points (h*w)
#define KD     288          // c*p*p
#define KE     576          // per-point row: [hi(288) | lo(288)] f16
#define NWIN   9            // 9 merged K-windows of 32 (hi+lo staged together)

typedef _Float16 f16;
typedef __attribute__((ext_vector_type(8))) _Float16 half8;
typedef __attribute__((ext_vector_type(16))) float floatx16;

#define AS1(p) ((const __attribute__((address_space(1))) uint32_t*)(p))
#define AS3(p) ((__attribute__((address_space(3))) uint32_t*)(p))

// -------- patch extraction + fp32->2xf16 split + fused norms/init ------------
__global__ void extract_split_kernel(const float* __restrict__ src,
                                     const float* __restrict__ tgt,
                                     f16* __restrict__ Aext,
                                     f16* __restrict__ Bext,
                                     float* __restrict__ rq,
                                     float* __restrict__ rp,
                                     unsigned long long* __restrict__ best) {
  int tid = blockIdx.x * 256 + threadIdx.x;   // 16384*32 threads
  int point = tid >> 5;
  int c = tid & 31;
  int y = point >> 7, x = point & 127;
  f16* arow = Aext + (size_t)point * KE;
  f16* brow = Bext + (size_t)point * KE;
  double sq = 0.0, sp = 0.0;
#pragma unroll
  for (int dy = 0; dy < 3; ++dy) {
    int yy = y + dy - 1; yy = yy < 0 ? 0 : (yy > 127 ? 127 : yy);
#pragma unroll
    for (int dx = 0; dx < 3; ++dx) {
      int xx = x + dx - 1; xx = xx < 0 ? 0 : (xx > 127 ? 127 : xx);
      int k = c * 9 + dy * 3 + dx;
      int m = (c << 14) + (yy << 7) + xx;
      float v = src[m];
      sq += (double)v * (double)v;
      f16 h = (f16)v;
      arow[k] = h; arow[KD + k] = (f16)(v - (float)h);
      v = tgt[m];
      sp += (double)v * (double)v;
      h = (f16)v;
      brow[k] = h; brow[KD + k] = (f16)(v - (float)h);
    }
  }
  // width-32 reduction over the 32 channels of this point (lanes share a wave:
  // lanes 0-31 = point A, lanes 32-63 = point B)
#pragma unroll
  for (int s = 1; s < 32; s <<= 1) {
    sq += __shfl_xor(sq, s, 32);
    sp += __shfl_xor(sp, s, 32);
  }
  if (c == 0) {
    rq[point] = (float)sq;
    rp[point] = (float)sp;
    best[point] = 0xFFFFFFFFFFFFFFFFULL;
  }
}

// ------ MFMA GEMM (merged split-products, 32x32x16 shape, single-buffer) -----
// LDS tile: 128 rows x 64 halves (8 slots of 8 halves = 16 B).
// Logical slice s of row r lives at phys slot (s ^ (r & 7)):
//   s in [0,4): hi window octet s (k = s*8..s*8+7);  s in [4,8): lo octet s-4.
// 32 KB LDS. No min-waves bound (round 6: forcing 5 waves/SIMD spilled the
// accumulator -> 7.4 GB scratch traffic). Natural ~150 regs -> 3 blocks/CU.
// Shape: 64x64 per wave as 2x2 tiles of mfma_f32_32x32x16_f16 (m119: 2495 TF
// vs 2075 for 16x16; half the issue slots, same LDS bytes).
__global__ __launch_bounds__(256)
void gemm_argmin_kernel(const f16* __restrict__ A, const f16* __restrict__ B,
                        const float* __restrict__ rq,
                        unsigned long long* __restrict__ best) {
  __shared__ f16 Ash[128 * 64];   // 16 KB
  __shared__ f16 Bsh[128 * 64];   // 16 KB

  const int nBase = blockIdx.x * 128;
  const int mBase = blockIdx.y * 128;
  const int t = threadIdx.x;
  const int w = t >> 6;           // wave 0..3
  const int l = t & 63;

  // ---- staging decode: per issue, 64 lanes cover 8 rows x 8 phys slots ----
  const int lr = l >> 3;                 // row within 8-row issue group
  const int lt = l & 7;                  // phys 16B slot
  const int sl = lt ^ (lr & 7);          // logical slice this lane fetches
  const int sColOff = (sl < 4) ? sl * 8 : KD + (sl & 3) * 8;  // + kw*32/window
  const f16* aBase[4];
  const f16* bBase[4];
#pragma unroll
  for (int ig = 0; ig < 4; ++ig) {
    int row = w * 32 + ig * 8 + lr;
    aBase[ig] = A + (size_t)(mBase + row) * KE + sColOff;
    bBase[ig] = B + (size_t)(nBase + row) * KE + sColOff;
  }

  // ---- fragment decode (32x32x16: A[m=lane&31][k=(lane>>5)*8+j]) ----
  const int m32 = l & 31;
  const int g   = l >> 5;                // k-half group within K16
  const int wRow = (w & 1) * 64;
  const int wCol = (w >> 1) * 64;

  floatx16 acc[2][2] = {};

#pragma unroll
  for (int kw = 0; kw < NWIN; ++kw) {
    __syncthreads();                     // previous window's reads complete
#pragma unroll
    for (int ig = 0; ig < 4; ++ig)
      __builtin_amdgcn_global_load_lds(AS1(aBase[ig] + kw * 32),
                                       AS3(&Ash[(w * 32 + ig * 8) * 64]), 16, 0, 0);
#pragma unroll
    for (int ig = 0; ig < 4; ++ig)
      __builtin_amdgcn_global_load_lds(AS1(bBase[ig] + kw * 32),
                                       AS3(&Bsh[(w * 32 + ig * 8) * 64]), 16, 0, 0);
    __syncthreads();                     // staging drained (vmcnt0 + barrier)

#pragma unroll
    for (int kh = 0; kh < 2; ++kh) {
      // hi octet for this K16 step: logical slot q = kh*2 + g, swizzled
      const int physHi = ((kh << 1) + g) ^ (m32 & 7);
      const int base = m32 * 64 + physHi * 8;   // halves; lo = base ^ 32
      half8 ah[2], bh[2], al[2], bl[2];
#pragma unroll
      for (int ti = 0; ti < 2; ++ti)
        ah[ti] = *(const half8*)&Ash[(wRow + ti * 32) * 64 + base];
#pragma unroll
      for (int tj = 0; tj < 2; ++tj)
        bh[tj] = *(const half8*)&Bsh[(wCol + tj * 32) * 64 + base];
#pragma unroll
      for (int ti = 0; ti < 2; ++ti)
        al[ti] = *(const half8*)&Ash[(wRow + ti * 32) * 64 + (base ^ 32)];
#pragma unroll
      for (int tj = 0; tj < 2; ++tj)
        bl[tj] = *(const half8*)&Bsh[(wCol + tj * 32) * 64 + (base ^ 32)];

      // hi.hi
#pragma unroll
      for (int ti = 0; ti < 2; ++ti)
#pragma unroll
        for (int tj = 0; tj < 2; ++tj)
          acc[ti][tj] = __builtin_amdgcn_mfma_f32_32x32x16_f16(ah[ti], bh[tj], acc[ti][tj], 0, 0, 0);
      // hi.lo
#pragma unroll
      for (int ti = 0; ti < 2; ++ti)
#pragma unroll
        for (int tj = 0; tj < 2; ++tj)
          acc[ti][tj] = __builtin_amdgcn_mfma_f32_32x32x16_f16(ah[ti], bl[tj], acc[ti][tj], 0, 0, 0);
      // lo.hi
#pragma unroll
      for (int ti = 0; ti < 2; ++ti)
#pragma unroll
        for (int tj = 0; tj < 2; ++tj)
          acc[ti][tj] = __builtin_amdgcn_mfma_f32_32x32x16_f16(al[ti], bh[tj], acc[ti][tj], 0, 0, 0);
    }
  }

  // ---- epilogue: f = rq[col] - 2*dot, packed argmin ----
  // C/D 32x32 layout (m74/m101): col = lane&31, row = (reg&3)+8*(reg>>2)+4*(lane>>5)
  const int colBase = nBase + wCol + m32;
  float rqv[2] = { rq[colBase], rq[colBase + 32] };

#pragma unroll
  for (int ti = 0; ti < 2; ++ti) {
#pragma unroll
    for (int reg = 0; reg < 16; ++reg) {
      const int rowG = mBase + wRow + ti * 32 + (reg & 3) + 8 * (reg >> 2) + 4 * g;
      float f0 = fmaf(-2.0f, acc[ti][0][reg], rqv[0]);
      unsigned int b0 = __float_as_uint(f0);
      b0 = (b0 & 0x80000000u) ? ~b0 : (b0 | 0x80000000u);
      unsigned long long pk =
          ((unsigned long long)b0 << 32) | (unsigned)colBase;
      float f1 = fmaf(-2.0f, acc[ti][1][reg], rqv[1]);
      unsigned int b1 = __float_as_uint(f1);
      b1 = (b1 & 0x80000000u) ? ~b1 : (b1 | 0x80000000u);
      unsigned long long c1 =
          ((unsigned long long)b1 << 32) | (unsigned)(colBase + 32);
      pk = pk < c1 ? pk : c1;
#pragma unroll
      for (int s = 1; s < 32; s <<= 1) {
        unsigned long long o = __shfl_xor(pk, s, 32);
        pk = pk < o ? pk : o;
      }
      if (m32 == 0) atomicMin(best + rowG, pk);
    }
  }
}

// ---------------------------- finalize ---------------------------------------
__global__ void finalize_kernel(const unsigned long long* __restrict__ best,
                                const float* __restrict__ rp,
                                float* __restrict__ out) {
  int i = blockIdx.x * 256 + threadIdx.x;
  if (i >= NPT) return;
  unsigned long long v = best[i];
  unsigned int col = (unsigned int)(v & 0xFFFFFFFFu);
  unsigned int key = (unsigned int)(v >> 32);
  unsigned int bits = (key & 0x80000000u) ? (key & 0x7FFFFFFFu) : ~key;
  float fmin = __uint_as_float(bits);
  out[i]           = (float)(col >> 7);   // idy
  out[NPT + i]     = (float)(col & 127);  // idx
  out[2 * NPT + i] = rp[i] + fmin;        // nnd
}

extern "C" void kernel_launch(void* const* d_in, const int* in_sizes, int n_in,
                              void* d_out, int out_size, void* d_ws, size_t ws_size,
                              hipStream_t stream) {
  const float* src = (const float*)d_in[0];  // source_map (1,32,128,128)
  const float* tgt = (const float*)d_in[1];  // target_map (1,32,128,128)
  float* out = (float*)d_out;

  // workspace layout (bytes):
  //   Aext: [0, 18874368)        16384 x 576 f16 (point-major [hi|lo])
  //   Bext: [18874368, 37748736)
  //   rq  : [37748736, 37814272) 16384 fp32 (target-side norms for the f-term)
  //   rp  : [37814272, 37879808)
  //   best: [37879808, 38010880) 16384 u64 packed (key<<32)|col
  char* ws = (char*)d_ws;
  f16* Aext = (f16*)(ws);
  f16* Bext = (f16*)(ws + 18874368);
  float* rq = (float*)(ws + 37748736);
  float* rp = (float*)(ws + 37814272);
  unsigned long long* best = (unsigned long long*)(ws + 37879808);

  extract_split_kernel<<<(NPT * 32) / 256, 256, 0, stream>>>(src, tgt, Aext, Bext,
                                                             rq, rp, best);
  {
    dim3 grid(128, 128);
    gemm_argmin_kernel<<<grid, 256, 0, stream>>>(Aext, Bext, rq, best);
  }
  finalize_kernel<<<NPT / 256, 256, 0, stream>>>(best, rp, out);
}